// Round 9
// baseline (330.327 us; speedup 1.0000x reference)
//
#include <hip/hip_runtime.h>
#include <hip/hip_bf16.h>

#define NN 50000
#define NE 800000
#define DH 128
#define NB1 196   // ceil(NN/256)
#define NBK 391   // ceil(NN/128) buckets
#define EPB 2048  // edges per bucket-scatter workgroup
#define CAPB 4096 // fixed bucket capacity (mean 2046, ~45 sigma headroom)
#define WPB 12500 // wave-groups (nodes/4) per phase

typedef __attribute__((ext_vector_type(8))) short bf16x8;
typedef __attribute__((ext_vector_type(4))) float f32x4;
typedef __attribute__((ext_vector_type(8))) unsigned short us8;
typedef __attribute__((ext_vector_type(4))) unsigned short us4;

__device__ __forceinline__ unsigned short f2bf(float f) {
  unsigned int u = __builtin_bit_cast(unsigned int, f);
  unsigned int r = (u + 0x7FFFu + ((u >> 16) & 1u)) >> 16;
  return (unsigned short)r;
}
__device__ __forceinline__ float bf2f(unsigned int h16) {
  unsigned int u = h16 << 16;
  return __builtin_bit_cast(float, u);
}

// ---- merged prep: cvt x->bf16 (blocks 0..3124), w1t (..3252), w2t (..3380), w3t (..3444)
__global__ __launch_bounds__(256) void k_prep(const float* __restrict__ x,
                                              const float* __restrict__ w1l, const float* __restrict__ w1r,
                                              const float* __restrict__ w2l, const float* __restrict__ w2r,
                                              const float* __restrict__ w3l, const float* __restrict__ w3r,
                                              unsigned short* __restrict__ xb,
                                              unsigned short* __restrict__ w1t,
                                              unsigned short* __restrict__ w2t,
                                              unsigned short* __restrict__ w3t) {
  int b = blockIdx.x, t = threadIdx.x;
  if (b < 3125) {
    int i = b * 256 + t;
    const float4* p = reinterpret_cast<const float4*>(x) + (size_t)i * 2;
    float4 a = p[0], bb = p[1];
    us8 o;
    o[0] = f2bf(a.x); o[1] = f2bf(a.y); o[2] = f2bf(a.z); o[3] = f2bf(a.w);
    o[4] = f2bf(bb.x); o[5] = f2bf(bb.y); o[6] = f2bf(bb.z); o[7] = f2bf(bb.w);
    reinterpret_cast<us8*>(xb)[i] = o;
  } else if (b < 3381) {
    bool is1 = b < 3253;
    int idx = (b - (is1 ? 3125 : 3253)) * 256 + t;
    int c = idx >> 8, k = idx & 255;
    const float* wl = is1 ? w1l : w2l;
    const float* wr = is1 ? w1r : w2r;
    float v = (k < DH) ? wl[k * DH + c] : wr[(k - DH) * DH + c];
    (is1 ? w1t : w2t)[idx] = f2bf(v);
  } else {
    int idx = (b - 3381) * 256 + t;
    int c = idx >> 7, k = idx & 127;
    float v = (c < 64) ? w3l[k * 64 + c] : w3r[k * 64 + (c - 64)];
    w3t[idx] = f2bf(v);
  }
}

// ---- bucket scatter: fixed-cap bucket regions, packed (src|dstlow) ----
__global__ __launch_bounds__(256) void k_bucket(const int* __restrict__ src,
                                                const int* __restrict__ dst,
                                                int* __restrict__ bcnt,
                                                int* __restrict__ ebuf) {
  __shared__ int lcnt[NBK], lbase[NBK];
  int t = threadIdx.x;
  for (int b = t; b < NBK; b += 256) lcnt[b] = 0;
  __syncthreads();
  int base = blockIdx.x * EPB;
  int d[8], s[8];
#pragma unroll
  for (int i = 0; i < 8; ++i) {
    int e = base + i * 256 + t;
    if (e < NE) { d[i] = dst[e]; s[i] = src[e]; }
    else d[i] = -1;
  }
#pragma unroll
  for (int i = 0; i < 8; ++i)
    if (d[i] >= 0) atomicAdd(&lcnt[d[i] >> 7], 1);
  __syncthreads();
  for (int b = t; b < NBK; b += 256) {
    int c = lcnt[b];
    lbase[b] = c > 0 ? atomicAdd(&bcnt[b], c) : 0;
    lcnt[b] = 0;
  }
  __syncthreads();
#pragma unroll
  for (int i = 0; i < 8; ++i) {
    if (d[i] >= 0) {
      int b = d[i] >> 7;
      int r = atomicAdd(&lcnt[b], 1);
      ebuf[(size_t)b * CAPB + lbase[b] + r] = s[i] | ((d[i] & 127) << 20);
    }
  }
}

// ---- per-bucket degree histogram -> deg, invd ----
__global__ __launch_bounds__(256) void k_hist(const int* __restrict__ bcnt,
                                              const int* __restrict__ ebuf,
                                              int* __restrict__ deg,
                                              float* __restrict__ invd) {
  int b = blockIdx.x;
  __shared__ int h[128];
  int t = threadIdx.x;
  if (t < 128) h[t] = 0;
  __syncthreads();
  int cnt = bcnt[b];
  const int* eb = ebuf + (size_t)b * CAPB;
  for (int e = t; e < cnt; e += 256)
    atomicAdd(&h[(eb[e] >> 20) & 127], 1);
  __syncthreads();
  int i = (b << 7) + t;
  if (t < 128 && i < NN) {
    int d = h[t];
    deg[i] = d;
    invd[i] = 1.0f / (float)(d > 0 ? d : 1);
  }
}

// ---- scans ----
__global__ void k_scan1(const int* __restrict__ deg, int* __restrict__ iscan,
                        int* __restrict__ bsum) {
  __shared__ int s[256];
  int t = threadIdx.x;
  int i = blockIdx.x * 256 + t;
  int d = (i < NN) ? deg[i] : 0;
  s[t] = d;
  __syncthreads();
  for (int off = 1; off < 256; off <<= 1) {
    int v = (t >= off) ? s[t - off] : 0;
    __syncthreads();
    s[t] += v;
    __syncthreads();
  }
  if (i < NN) iscan[i] = s[t];
  if (t == 255) bsum[blockIdx.x] = s[255];
}

__global__ void k_scan2(int* __restrict__ bsum) {
  __shared__ int s[256];
  int t = threadIdx.x;
  int v = (t < NB1) ? bsum[t] : 0;
  s[t] = v;
  __syncthreads();
  for (int off = 1; off < 256; off <<= 1) {
    int u = (t >= off) ? s[t - off] : 0;
    __syncthreads();
    s[t] += u;
    __syncthreads();
  }
  if (t < NB1) bsum[t] = s[t] - v;
}

__global__ void k_scan3(const int* __restrict__ deg, const int* __restrict__ iscan,
                        const int* __restrict__ bsum, int* __restrict__ rowptr) {
  int i = blockIdx.x * 256 + threadIdx.x;
  if (i >= NN) return;
  int excl = bsum[blockIdx.x] + iscan[i] - deg[i];
  rowptr[i] = excl;
  if (i == 0) rowptr[NN] = NE;
}

// ---- per-bucket CSR fill ----
__global__ __launch_bounds__(256) void k_fill2(const int* __restrict__ rowptr,
                                               const int* __restrict__ bcnt,
                                               const int* __restrict__ ebuf,
                                               int* __restrict__ adj) {
  int b = blockIdx.x;
  int n0 = b << 7;
  int n1 = n0 + 128; if (n1 > NN) n1 = NN;
  __shared__ int cur[128];
  int t = threadIdx.x;
  if (t < n1 - n0) cur[t] = rowptr[n0 + t];
  __syncthreads();
  int cnt = bcnt[b];
  const int* eb = ebuf + (size_t)b * CAPB;
  for (int e = t; e < cnt; e += 256) {
    int p = eb[e];
    int pos = atomicAdd(&cur[(p >> 20) & 127], 1);
    adj[pos] = p & 0xFFFFF;
  }
}

// ---- BN scale/shift table: bnt[c] = (sc, sh) ----
__global__ void k_bnprep(const float* __restrict__ stats, const float* __restrict__ g,
                         const float* __restrict__ be, float2* __restrict__ bnt) {
  int t = threadIdx.x;
  if (t >= 128) return;
  float mu = stats[t] * (1.0f / NN);
  float var = stats[128 + t] * (1.0f / NN) - mu * mu;
  float rs = rsqrtf(var + 1e-5f);
  float scv = rs * g[t];
  bnt[t] = make_float2(scv, be[t] - mu * scv);
}

// ---- phase-split gather-mean: wave per (node, 32-col phase); 8 lanes/edge x 8B;
//      8 edges in flight; per-phase working set 3.2MB fits per-XCD L2 ----
template <bool BNA>
__global__ __launch_bounds__(256) void k_agg(const unsigned short* __restrict__ h,
                                             const int* __restrict__ rowptr,
                                             const int* __restrict__ adj,
                                             const float* __restrict__ invd,
                                             const float2* __restrict__ bnt,
                                             unsigned short* __restrict__ meanb) {
  int bid = blockIdx.x;
  int ph = bid / WPB;  // 0..3
  int node = (bid - ph * WPB) * 4 + (threadIdx.x >> 6);
  int lane = threadIdx.x & 63;
  int q = lane >> 3;   // edge slot 0..7
  int cc = lane & 7;   // 8B chunk within 64B line
  int cbase = ph * 32 + cc * 4;
  float sc[4], sh[4];
  if (BNA) {
#pragma unroll
    for (int j = 0; j < 4; ++j) {
      float2 v = bnt[cbase + j];
      sc[j] = v.x; sh[j] = v.y;
    }
  }
  int lo = rowptr[node], hi = rowptr[node + 1];
  const unsigned short* hb = h + cbase;
  float a[4] = {};
  int e = lo;
  for (; e + 8 <= hi; e += 8) {
    int s = adj[e + q];
    us4 v = *reinterpret_cast<const us4*>(hb + (size_t)s * DH);
#pragma unroll
    for (int j = 0; j < 4; ++j) {
      float f = bf2f(v[j]);
      a[j] += BNA ? fmaxf(fmaf(f, sc[j], sh[j]), 0.0f) : f;
    }
  }
  if (q < hi - e) {
    int s = adj[e + q];
    us4 v = *reinterpret_cast<const us4*>(hb + (size_t)s * DH);
#pragma unroll
    for (int j = 0; j < 4; ++j) {
      float f = bf2f(v[j]);
      a[j] += BNA ? fmaxf(fmaf(f, sc[j], sh[j]), 0.0f) : f;
    }
  }
#pragma unroll
  for (int j = 0; j < 4; ++j) {
    a[j] += __shfl_xor(a[j], 8);
    a[j] += __shfl_xor(a[j], 16);
    a[j] += __shfl_xor(a[j], 32);
  }
  if (lane < 8) {
    float iv = invd[node];
    us4 o;
#pragma unroll
    for (int j = 0; j < 4; ++j) o[j] = f2bf(a[j] * iv);
    *reinterpret_cast<us4*>(meanb + (size_t)node * DH + ph * 32 + lane * 4) = o;
  }
}

// ---- layer-3 agg: 2 phases over 64 gathered cols; + self + b3 -> f32 out ----
__global__ __launch_bounds__(256) void k_agg3(const unsigned short* __restrict__ t3,
                                              const int* __restrict__ rowptr,
                                              const int* __restrict__ adj,
                                              const float* __restrict__ invd,
                                              const float* __restrict__ b3,
                                              float* __restrict__ out) {
  int bid = blockIdx.x;
  int ph = bid / WPB;  // 0..1
  int node = (bid - ph * WPB) * 4 + (threadIdx.x >> 6);
  int lane = threadIdx.x & 63;
  int q = lane >> 3;
  int cc = lane & 7;
  int cbase = ph * 32 + cc * 4;
  int lo = rowptr[node], hi = rowptr[node + 1];
  const unsigned short* tb = t3 + cbase;
  float a[4] = {};
  int e = lo;
  for (; e + 8 <= hi; e += 8) {
    int s = adj[e + q];
    us4 v = *reinterpret_cast<const us4*>(tb + (size_t)s * 128);
#pragma unroll
    for (int j = 0; j < 4; ++j) a[j] += bf2f(v[j]);
  }
  if (q < hi - e) {
    int s = adj[e + q];
    us4 v = *reinterpret_cast<const us4*>(tb + (size_t)s * 128);
#pragma unroll
    for (int j = 0; j < 4; ++j) a[j] += bf2f(v[j]);
  }
#pragma unroll
  for (int j = 0; j < 4; ++j) {
    a[j] += __shfl_xor(a[j], 8);
    a[j] += __shfl_xor(a[j], 16);
    a[j] += __shfl_xor(a[j], 32);
  }
  if (lane < 8) {
    float iv = invd[node];
    int cb = ph * 32 + lane * 4;
    us4 w = *reinterpret_cast<const us4*>(t3 + (size_t)node * 128 + 64 + cb);
    float4 o;
    o.x = a[0] * iv + bf2f(w[0]) + b3[cb + 0];
    o.y = a[1] * iv + bf2f(w[1]) + b3[cb + 1];
    o.z = a[2] * iv + bf2f(w[2]) + b3[cb + 2];
    o.w = a[3] * iv + bf2f(w[3]) + b3[cb + 3];
    *reinterpret_cast<float4*>(out + (size_t)node * 64 + cb) = o;
  }
}

// ---- GEMM with optional fused BN+ReLU on the raw-gemm-out A operand ----
template <bool SPLIT, bool STATS, bool APPLY>
__global__ __launch_bounds__(256) void k_gemm(const unsigned short* __restrict__ Am,
                                              const unsigned short* __restrict__ Ah,
                                              const unsigned short* __restrict__ Wt,
                                              const float* __restrict__ bias,
                                              const float* __restrict__ stA,
                                              const float* __restrict__ gA,
                                              const float* __restrict__ beA,
                                              unsigned short* __restrict__ outb,
                                              float* __restrict__ stats) {
  constexpr int KS = SPLIT ? 8 : 4;
  constexpr int WK = KS * 32;
  __shared__ float asc[DH], ash[DH];
  if (APPLY) {
    int t = threadIdx.x;
    if (t < DH) {
      float mu = stA[t] * (1.0f / NN);
      float var = stA[128 + t] * (1.0f / NN) - mu * mu;
      float rs = rsqrtf(var + 1e-5f);
      float scv = rs * gA[t];
      asc[t] = scv;
      ash[t] = beA[t] - mu * scv;
    }
    __syncthreads();
  }
  int lane = threadIdx.x & 63;
  int w = threadIdx.x >> 6;
  int wr = w >> 1, wc = w & 1;
  int rowbase = blockIdx.x * 128 + wr * 64;
  int colbase = wc * 64;
  int lr = lane & 15, lk = (lane >> 4) << 3;

  f32x4 acc[4][4] = {};
#pragma unroll
  for (int ks = 0; ks < KS; ++ks) {
    const unsigned short* Ab = (!SPLIT || ks < 4) ? Am : Ah;
    bool tr = APPLY && (!SPLIT || ks >= 4);
    int ka = ((ks & 3) << 5) + lk;
    int kw = (ks << 5) + lk;
    bf16x8 af[4], bfr[4];
#pragma unroll
    for (int i = 0; i < 4; ++i) {
      int r = rowbase + i * 16 + lr;
      r = r < NN ? r : NN - 1;
      us8 raw = *reinterpret_cast<const us8*>(Ab + (size_t)r * DH + ka);
      if (tr) {
        us8 o;
#pragma unroll
        for (int j = 0; j < 8; ++j) {
          float f = bf2f(raw[j]);
          o[j] = f2bf(fmaxf(f * asc[ka + j] + ash[ka + j], 0.0f));
        }
        af[i] = __builtin_bit_cast(bf16x8, o);
      } else {
        af[i] = __builtin_bit_cast(bf16x8, raw);
      }
    }
#pragma unroll
    for (int j = 0; j < 4; ++j)
      bfr[j] = *reinterpret_cast<const bf16x8*>(Wt + (size_t)(colbase + j * 16 + lr) * WK + kw);
#pragma unroll
    for (int i = 0; i < 4; ++i)
#pragma unroll
      for (int j = 0; j < 4; ++j)
        acc[i][j] = __builtin_amdgcn_mfma_f32_16x16x32_bf16(af[i], bfr[j], acc[i][j], 0, 0, 0);
  }

  float bv[4];
#pragma unroll
  for (int j = 0; j < 4; ++j) bv[j] = bias ? bias[colbase + j * 16 + lr] : 0.0f;

  float s1[4] = {}, s2[4] = {};
#pragma unroll
  for (int i = 0; i < 4; ++i) {
#pragma unroll
    for (int j = 0; j < 4; ++j) {
      int col = colbase + j * 16 + lr;
#pragma unroll
      for (int r = 0; r < 4; ++r) {
        int row = rowbase + i * 16 + ((lane >> 4) << 2) + r;
        if (row < NN) {
          float val = acc[i][j][r] + bv[j];
          outb[(size_t)row * 128 + col] = f2bf(val);
          if (STATS) { s1[j] += val; s2[j] += val * val; }
        }
      }
    }
  }

  if (STATS) {
    __shared__ float sd[2][128][2];
#pragma unroll
    for (int j = 0; j < 4; ++j) {
      s1[j] += __shfl_xor(s1[j], 16);
      s1[j] += __shfl_xor(s1[j], 32);
      s2[j] += __shfl_xor(s2[j], 16);
      s2[j] += __shfl_xor(s2[j], 32);
    }
    if (lane < 16) {
#pragma unroll
      for (int j = 0; j < 4; ++j) {
        sd[wr][colbase + j * 16 + lane][0] = s1[j];
        sd[wr][colbase + j * 16 + lane][1] = s2[j];
      }
    }
    __syncthreads();
    int t = threadIdx.x;
    if (t < 128) {
      atomicAdd(&stats[t], sd[0][t][0] + sd[1][t][0]);
      atomicAdd(&stats[128 + t], sd[0][t][1] + sd[1][t][1]);
    }
  }
}

extern "C" void kernel_launch(void* const* d_in, const int* in_sizes, int n_in,
                              void* d_out, int out_size, void* d_ws, size_t ws_size,
                              hipStream_t stream) {
  const float* x = (const float*)d_in[0];
  const int* ei = (const int*)d_in[1];
  const int* srcp = ei;
  const int* dstp = ei + NE;
  const float* w1l = (const float*)d_in[2];
  const float* w1r = (const float*)d_in[3];
  const float* b1 = (const float*)d_in[4];
  const float* g1 = (const float*)d_in[5];
  const float* be1 = (const float*)d_in[6];
  const float* w2l = (const float*)d_in[7];
  const float* w2r = (const float*)d_in[8];
  const float* b2 = (const float*)d_in[9];
  const float* g2 = (const float*)d_in[10];
  const float* be2 = (const float*)d_in[11];
  const float* w3l = (const float*)d_in[12];
  const float* w3r = (const float*)d_in[13];
  const float* b3 = (const float*)d_in[14];

  char* ws = (char*)d_ws;
  size_t off = 0;
  auto alloc = [&](size_t bytes) {
    char* p = ws + off;
    off = (off + bytes + 255) & ~(size_t)255;
    return p;
  };
  unsigned short* xb = (unsigned short*)alloc((size_t)NN * DH * 2);
  unsigned short* meanb = (unsigned short*)alloc((size_t)NN * DH * 2);
  unsigned short* gbuf1 = (unsigned short*)alloc((size_t)NN * DH * 2);
  unsigned short* gbuf2 = (unsigned short*)alloc((size_t)NN * DH * 2);
  unsigned short* w1t = (unsigned short*)alloc(128 * 256 * 2);
  unsigned short* w2t = (unsigned short*)alloc(128 * 256 * 2);
  unsigned short* w3t = (unsigned short*)alloc(128 * 128 * 2);
  // zero region: bcnt | stats1 | stats2 (contiguous)
  int* bcnt = (int*)alloc(NBK * 4);
  float* stats1 = (float*)alloc(2 * DH * 4);
  float* stats2 = (float*)alloc(2 * DH * 4);
  size_t zlen = (char*)(stats2 + 2 * DH) - (char*)bcnt;
  int* deg = (int*)alloc(NN * 4);
  int* rowptr = (int*)alloc((NN + 1) * 4);
  int* adj = (int*)alloc((size_t)NE * 4);
  int* ebuf = (int*)alloc((size_t)NBK * CAPB * 4);
  float* invd = (float*)alloc(NN * 4);
  int* iscan = (int*)alloc(NN * 4);
  int* bsum = (int*)alloc(NB1 * 4);
  float2* bnt1 = (float2*)alloc(DH * 8);

  // ---- prep ----
  hipMemsetAsync(bcnt, 0, zlen, stream);
  k_prep<<<3445, 256, 0, stream>>>(x, w1l, w1r, w2l, w2r, w3l, w3r, xb, w1t, w2t, w3t);
  k_bucket<<<(NE + EPB - 1) / EPB, 256, 0, stream>>>(srcp, dstp, bcnt, ebuf);
  k_hist<<<NBK, 256, 0, stream>>>(bcnt, ebuf, deg, invd);
  k_scan1<<<NB1, 256, 0, stream>>>(deg, iscan, bsum);
  k_scan2<<<1, 256, 0, stream>>>(bsum);
  k_scan3<<<NB1, 256, 0, stream>>>(deg, iscan, bsum, rowptr);
  k_fill2<<<NBK, 256, 0, stream>>>(rowptr, bcnt, ebuf, adj);

  int gemm_blocks = (NN + 127) / 128;

  // ---- layer 1 ----
  k_agg<false><<<4 * WPB, 256, 0, stream>>>(xb, rowptr, adj, invd, nullptr, meanb);
  k_gemm<true, true, false><<<gemm_blocks, 256, 0, stream>>>(
      meanb, xb, w1t, b1, nullptr, nullptr, nullptr, gbuf1, stats1);
  k_bnprep<<<1, 128, 0, stream>>>(stats1, g1, be1, bnt1);

  // ---- layer 2 (BN1+ReLU fused: agg via table, gemm A-load self-computed) ----
  k_agg<true><<<4 * WPB, 256, 0, stream>>>(gbuf1, rowptr, adj, invd, bnt1, meanb);
  k_gemm<true, true, true><<<gemm_blocks, 256, 0, stream>>>(
      meanb, gbuf1, w2t, b2, stats1, g1, be1, gbuf2, stats2);

  // ---- layer 3: transform-first (BN2+ReLU fused into gemm A-load), then aggregate ----
  k_gemm<false, false, true><<<gemm_blocks, 256, 0, stream>>>(
      gbuf2, nullptr, w3t, nullptr, stats2, g2, be2, gbuf1, nullptr);
  k_agg3<<<2 * WPB, 256, 0, stream>>>(gbuf1, rowptr, adj, invd, b3, (float*)d_out);
}

// Round 10
// 249.477 us; speedup vs baseline: 1.3241x; 1.3241x over previous
//
#include <hip/hip_runtime.h>
#include <hip/hip_bf16.h>

#define NN 50000
#define NE 800000
#define DH 128
#define NB1 196   // ceil(NN/256)
#define NBK 391   // ceil(NN/128) buckets
#define EPB 2048  // edges per bucket-scatter workgroup
#define CAPB 4096 // fixed bucket capacity (mean 2046, ~45 sigma headroom)
#define APB 12500 // agg blocks per phase (4 nodes/block)

typedef __attribute__((ext_vector_type(8))) short bf16x8;
typedef __attribute__((ext_vector_type(4))) float f32x4;
typedef __attribute__((ext_vector_type(8))) unsigned short us8;
typedef __attribute__((ext_vector_type(4))) unsigned short us4;

__device__ __forceinline__ unsigned short f2bf(float f) {
  unsigned int u = __builtin_bit_cast(unsigned int, f);
  unsigned int r = (u + 0x7FFFu + ((u >> 16) & 1u)) >> 16;
  return (unsigned short)r;
}
__device__ __forceinline__ float bf2f(unsigned int h16) {
  unsigned int u = h16 << 16;
  return __builtin_bit_cast(float, u);
}

// ---- merged prep: cvt x->bf16 (blocks 0..3124), w1t (..3252), w2t (..3380), w3t (..3444)
__global__ __launch_bounds__(256) void k_prep(const float* __restrict__ x,
                                              const float* __restrict__ w1l, const float* __restrict__ w1r,
                                              const float* __restrict__ w2l, const float* __restrict__ w2r,
                                              const float* __restrict__ w3l, const float* __restrict__ w3r,
                                              unsigned short* __restrict__ xb,
                                              unsigned short* __restrict__ w1t,
                                              unsigned short* __restrict__ w2t,
                                              unsigned short* __restrict__ w3t) {
  int b = blockIdx.x, t = threadIdx.x;
  if (b < 3125) {
    int i = b * 256 + t;
    const float4* p = reinterpret_cast<const float4*>(x) + (size_t)i * 2;
    float4 a = p[0], bb = p[1];
    us8 o;
    o[0] = f2bf(a.x); o[1] = f2bf(a.y); o[2] = f2bf(a.z); o[3] = f2bf(a.w);
    o[4] = f2bf(bb.x); o[5] = f2bf(bb.y); o[6] = f2bf(bb.z); o[7] = f2bf(bb.w);
    reinterpret_cast<us8*>(xb)[i] = o;
  } else if (b < 3381) {
    bool is1 = b < 3253;
    int idx = (b - (is1 ? 3125 : 3253)) * 256 + t;
    int c = idx >> 8, k = idx & 255;
    const float* wl = is1 ? w1l : w2l;
    const float* wr = is1 ? w1r : w2r;
    float v = (k < DH) ? wl[k * DH + c] : wr[(k - DH) * DH + c];
    (is1 ? w1t : w2t)[idx] = f2bf(v);
  } else {
    int idx = (b - 3381) * 256 + t;
    int c = idx >> 7, k = idx & 127;
    float v = (c < 64) ? w3l[k * 64 + c] : w3r[k * 64 + (c - 64)];
    w3t[idx] = f2bf(v);
  }
}

// ---- bucket scatter: fixed-cap bucket regions, packed (src|dstlow) ----
__global__ __launch_bounds__(256) void k_bucket(const int* __restrict__ src,
                                                const int* __restrict__ dst,
                                                int* __restrict__ bcnt,
                                                int* __restrict__ ebuf) {
  __shared__ int lcnt[NBK], lbase[NBK];
  int t = threadIdx.x;
  for (int b = t; b < NBK; b += 256) lcnt[b] = 0;
  __syncthreads();
  int base = blockIdx.x * EPB;
  int d[8], s[8];
#pragma unroll
  for (int i = 0; i < 8; ++i) {
    int e = base + i * 256 + t;
    if (e < NE) { d[i] = dst[e]; s[i] = src[e]; }
    else d[i] = -1;
  }
#pragma unroll
  for (int i = 0; i < 8; ++i)
    if (d[i] >= 0) atomicAdd(&lcnt[d[i] >> 7], 1);
  __syncthreads();
  for (int b = t; b < NBK; b += 256) {
    int c = lcnt[b];
    lbase[b] = c > 0 ? atomicAdd(&bcnt[b], c) : 0;
    lcnt[b] = 0;
  }
  __syncthreads();
#pragma unroll
  for (int i = 0; i < 8; ++i) {
    if (d[i] >= 0) {
      int b = d[i] >> 7;
      int r = atomicAdd(&lcnt[b], 1);
      ebuf[(size_t)b * CAPB + lbase[b] + r] = s[i] | ((d[i] & 127) << 20);
    }
  }
}

// ---- per-bucket degree histogram -> deg, invd ----
__global__ __launch_bounds__(256) void k_hist(const int* __restrict__ bcnt,
                                              const int* __restrict__ ebuf,
                                              int* __restrict__ deg,
                                              float* __restrict__ invd) {
  int b = blockIdx.x;
  __shared__ int h[128];
  int t = threadIdx.x;
  if (t < 128) h[t] = 0;
  __syncthreads();
  int cnt = bcnt[b];
  const int* eb = ebuf + (size_t)b * CAPB;
  for (int e = t; e < cnt; e += 256)
    atomicAdd(&h[(eb[e] >> 20) & 127], 1);
  __syncthreads();
  int i = (b << 7) + t;
  if (t < 128 && i < NN) {
    int d = h[t];
    deg[i] = d;
    invd[i] = 1.0f / (float)(d > 0 ? d : 1);
  }
}

// ---- scans ----
__global__ void k_scan1(const int* __restrict__ deg, int* __restrict__ iscan,
                        int* __restrict__ bsum) {
  __shared__ int s[256];
  int t = threadIdx.x;
  int i = blockIdx.x * 256 + t;
  int d = (i < NN) ? deg[i] : 0;
  s[t] = d;
  __syncthreads();
  for (int off = 1; off < 256; off <<= 1) {
    int v = (t >= off) ? s[t - off] : 0;
    __syncthreads();
    s[t] += v;
    __syncthreads();
  }
  if (i < NN) iscan[i] = s[t];
  if (t == 255) bsum[blockIdx.x] = s[255];
}

__global__ void k_scan2(int* __restrict__ bsum) {
  __shared__ int s[256];
  int t = threadIdx.x;
  int v = (t < NB1) ? bsum[t] : 0;
  s[t] = v;
  __syncthreads();
  for (int off = 1; off < 256; off <<= 1) {
    int u = (t >= off) ? s[t - off] : 0;
    __syncthreads();
    s[t] += u;
    __syncthreads();
  }
  if (t < NB1) bsum[t] = s[t] - v;
}

__global__ void k_scan3(const int* __restrict__ deg, const int* __restrict__ iscan,
                        const int* __restrict__ bsum, int* __restrict__ rowptr) {
  int i = blockIdx.x * 256 + threadIdx.x;
  if (i >= NN) return;
  int excl = bsum[blockIdx.x] + iscan[i] - deg[i];
  rowptr[i] = excl;
  if (i == 0) rowptr[NN] = NE;
}

// ---- per-bucket CSR fill ----
__global__ __launch_bounds__(256) void k_fill2(const int* __restrict__ rowptr,
                                               const int* __restrict__ bcnt,
                                               const int* __restrict__ ebuf,
                                               int* __restrict__ adj) {
  int b = blockIdx.x;
  int n0 = b << 7;
  int n1 = n0 + 128; if (n1 > NN) n1 = NN;
  __shared__ int cur[128];
  int t = threadIdx.x;
  if (t < n1 - n0) cur[t] = rowptr[n0 + t];
  __syncthreads();
  int cnt = bcnt[b];
  const int* eb = ebuf + (size_t)b * CAPB;
  for (int e = t; e < cnt; e += 256) {
    int p = eb[e];
    int pos = atomicAdd(&cur[(p >> 20) & 127], 1);
    adj[pos] = p & 0xFFFFF;
  }
}

// ---- BN scale/shift table: bnt[c] = (sc, sh) ----
__global__ void k_bnprep(const float* __restrict__ stats, const float* __restrict__ g,
                         const float* __restrict__ be, float2* __restrict__ bnt) {
  int t = threadIdx.x;
  if (t >= 128) return;
  float mu = stats[t] * (1.0f / NN);
  float var = stats[128 + t] * (1.0f / NN) - mu * mu;
  float rs = rsqrtf(var + 1e-5f);
  float scv = rs * g[t];
  bnt[t] = make_float2(scv, be[t] - mu * scv);
}

// ---- 2-phase gather-mean: wave/node, per phase one 128B line/edge (64 cols),
//      16-lane quarters x 8B, 4 edges in flight; optional BN+ReLU via table ----
template <bool BNA>
__global__ __launch_bounds__(256) void k_agg(const unsigned short* __restrict__ h,
                                             const int* __restrict__ rowptr,
                                             const int* __restrict__ adj,
                                             const float* __restrict__ invd,
                                             const float2* __restrict__ bnt,
                                             unsigned short* __restrict__ meanb) {
  int bid = blockIdx.x;
  int ph = bid / APB;  // 0..1
  int node = (bid - ph * APB) * 4 + (threadIdx.x >> 6);
  int lane = threadIdx.x & 63;
  int q = lane >> 4;
  int cbase = ph * 64 + (lane & 15) * 4;
  float sc[4], sh[4];
  if (BNA) {
#pragma unroll
    for (int j = 0; j < 4; ++j) {
      float2 v = bnt[cbase + j];
      sc[j] = v.x; sh[j] = v.y;
    }
  }
  int lo = rowptr[node], hi = rowptr[node + 1];
  const unsigned short* hb = h + cbase;
  float a[4] = {};
  int e = lo;
#pragma unroll 2
  for (; e + 4 <= hi; e += 4) {
    int s = adj[e + q];
    us4 v = *reinterpret_cast<const us4*>(hb + (size_t)s * DH);
#pragma unroll
    for (int j = 0; j < 4; ++j) {
      float f = bf2f(v[j]);
      a[j] += BNA ? fmaxf(fmaf(f, sc[j], sh[j]), 0.0f) : f;
    }
  }
  if (q < hi - e) {
    int s = adj[e + q];
    us4 v = *reinterpret_cast<const us4*>(hb + (size_t)s * DH);
#pragma unroll
    for (int j = 0; j < 4; ++j) {
      float f = bf2f(v[j]);
      a[j] += BNA ? fmaxf(fmaf(f, sc[j], sh[j]), 0.0f) : f;
    }
  }
#pragma unroll
  for (int j = 0; j < 4; ++j) {
    a[j] += __shfl_xor(a[j], 16);
    a[j] += __shfl_xor(a[j], 32);
  }
  if (lane < 16) {
    float iv = invd[node];
    us4 o;
#pragma unroll
    for (int j = 0; j < 4; ++j) o[j] = f2bf(a[j] * iv);
    *reinterpret_cast<us4*>(meanb + (size_t)node * DH + ph * 64 + lane * 4) = o;
  }
}

// ---- layer-3 agg (R6 form): one 128B line/edge already; + self + b3 -> f32 ----
__global__ __launch_bounds__(256) void k_agg3(const unsigned short* __restrict__ t3,
                                              const int* __restrict__ rowptr,
                                              const int* __restrict__ adj,
                                              const float* __restrict__ invd,
                                              const float* __restrict__ b3,
                                              float* __restrict__ out) {
  int wid = (blockIdx.x * blockDim.x + threadIdx.x) >> 6;
  int lane = threadIdx.x & 63;
  if (wid >= NN) return;
  int lo = rowptr[wid], hi = rowptr[wid + 1];
  int q = lane >> 4;
  int c = (lane & 15) << 2;
  float a[4] = {};
  int e = lo;
#pragma unroll 2
  for (; e + 4 <= hi; e += 4) {
    int s = adj[e + q];
    us4 v = *reinterpret_cast<const us4*>(t3 + (size_t)s * 128 + c);
#pragma unroll
    for (int j = 0; j < 4; ++j) a[j] += bf2f(v[j]);
  }
  if (q < hi - e) {
    int s = adj[e + q];
    us4 v = *reinterpret_cast<const us4*>(t3 + (size_t)s * 128 + c);
#pragma unroll
    for (int j = 0; j < 4; ++j) a[j] += bf2f(v[j]);
  }
#pragma unroll
  for (int j = 0; j < 4; ++j) {
    a[j] += __shfl_xor(a[j], 16);
    a[j] += __shfl_xor(a[j], 32);
  }
  if (q == 0) {
    float iv = invd[wid];
    us4 w = *reinterpret_cast<const us4*>(t3 + (size_t)wid * 128 + 64 + c);
    float4 o;
    o.x = a[0] * iv + bf2f(w[0]) + b3[c + 0];
    o.y = a[1] * iv + bf2f(w[1]) + b3[c + 1];
    o.z = a[2] * iv + bf2f(w[2]) + b3[c + 2];
    o.w = a[3] * iv + bf2f(w[3]) + b3[c + 3];
    *reinterpret_cast<float4*>(out + (size_t)wid * 64 + c) = o;
  }
}

// ---- GEMM with optional fused BN+ReLU on the raw-gemm-out A operand ----
template <bool SPLIT, bool STATS, bool APPLY>
__global__ __launch_bounds__(256) void k_gemm(const unsigned short* __restrict__ Am,
                                              const unsigned short* __restrict__ Ah,
                                              const unsigned short* __restrict__ Wt,
                                              const float* __restrict__ bias,
                                              const float* __restrict__ stA,
                                              const float* __restrict__ gA,
                                              const float* __restrict__ beA,
                                              unsigned short* __restrict__ outb,
                                              float* __restrict__ stats) {
  constexpr int KS = SPLIT ? 8 : 4;
  constexpr int WK = KS * 32;
  __shared__ float asc[DH], ash[DH];
  if (APPLY) {
    int t = threadIdx.x;
    if (t < DH) {
      float mu = stA[t] * (1.0f / NN);
      float var = stA[128 + t] * (1.0f / NN) - mu * mu;
      float rs = rsqrtf(var + 1e-5f);
      float scv = rs * gA[t];
      asc[t] = scv;
      ash[t] = beA[t] - mu * scv;
    }
    __syncthreads();
  }
  int lane = threadIdx.x & 63;
  int w = threadIdx.x >> 6;
  int wr = w >> 1, wc = w & 1;
  int rowbase = blockIdx.x * 128 + wr * 64;
  int colbase = wc * 64;
  int lr = lane & 15, lk = (lane >> 4) << 3;

  f32x4 acc[4][4] = {};
#pragma unroll
  for (int ks = 0; ks < KS; ++ks) {
    const unsigned short* Ab = (!SPLIT || ks < 4) ? Am : Ah;
    bool tr = APPLY && (!SPLIT || ks >= 4);
    int ka = ((ks & 3) << 5) + lk;
    int kw = (ks << 5) + lk;
    bf16x8 af[4], bfr[4];
#pragma unroll
    for (int i = 0; i < 4; ++i) {
      int r = rowbase + i * 16 + lr;
      r = r < NN ? r : NN - 1;
      us8 raw = *reinterpret_cast<const us8*>(Ab + (size_t)r * DH + ka);
      if (tr) {
        us8 o;
#pragma unroll
        for (int j = 0; j < 8; ++j) {
          float f = bf2f(raw[j]);
          o[j] = f2bf(fmaxf(f * asc[ka + j] + ash[ka + j], 0.0f));
        }
        af[i] = __builtin_bit_cast(bf16x8, o);
      } else {
        af[i] = __builtin_bit_cast(bf16x8, raw);
      }
    }
#pragma unroll
    for (int j = 0; j < 4; ++j)
      bfr[j] = *reinterpret_cast<const bf16x8*>(Wt + (size_t)(colbase + j * 16 + lr) * WK + kw);
#pragma unroll
    for (int i = 0; i < 4; ++i)
#pragma unroll
      for (int j = 0; j < 4; ++j)
        acc[i][j] = __builtin_amdgcn_mfma_f32_16x16x32_bf16(af[i], bfr[j], acc[i][j], 0, 0, 0);
  }

  float bv[4];
#pragma unroll
  for (int j = 0; j < 4; ++j) bv[j] = bias ? bias[colbase + j * 16 + lr] : 0.0f;

  float s1[4] = {}, s2[4] = {};
#pragma unroll
  for (int i = 0; i < 4; ++i) {
#pragma unroll
    for (int j = 0; j < 4; ++j) {
      int col = colbase + j * 16 + lr;
#pragma unroll
      for (int r = 0; r < 4; ++r) {
        int row = rowbase + i * 16 + ((lane >> 4) << 2) + r;
        if (row < NN) {
          float val = acc[i][j][r] + bv[j];
          outb[(size_t)row * 128 + col] = f2bf(val);
          if (STATS) { s1[j] += val; s2[j] += val * val; }
        }
      }
    }
  }

  if (STATS) {
    __shared__ float sd[2][128][2];
#pragma unroll
    for (int j = 0; j < 4; ++j) {
      s1[j] += __shfl_xor(s1[j], 16);
      s1[j] += __shfl_xor(s1[j], 32);
      s2[j] += __shfl_xor(s2[j], 16);
      s2[j] += __shfl_xor(s2[j], 32);
    }
    if (lane < 16) {
#pragma unroll
      for (int j = 0; j < 4; ++j) {
        sd[wr][colbase + j * 16 + lane][0] = s1[j];
        sd[wr][colbase + j * 16 + lane][1] = s2[j];
      }
    }
    __syncthreads();
    int t = threadIdx.x;
    if (t < 128) {
      atomicAdd(&stats[t], sd[0][t][0] + sd[1][t][0]);
      atomicAdd(&stats[128 + t], sd[0][t][1] + sd[1][t][1]);
    }
  }
}

extern "C" void kernel_launch(void* const* d_in, const int* in_sizes, int n_in,
                              void* d_out, int out_size, void* d_ws, size_t ws_size,
                              hipStream_t stream) {
  const float* x = (const float*)d_in[0];
  const int* ei = (const int*)d_in[1];
  const int* srcp = ei;
  const int* dstp = ei + NE;
  const float* w1l = (const float*)d_in[2];
  const float* w1r = (const float*)d_in[3];
  const float* b1 = (const float*)d_in[4];
  const float* g1 = (const float*)d_in[5];
  const float* be1 = (const float*)d_in[6];
  const float* w2l = (const float*)d_in[7];
  const float* w2r = (const float*)d_in[8];
  const float* b2 = (const float*)d_in[9];
  const float* g2 = (const float*)d_in[10];
  const float* be2 = (const float*)d_in[11];
  const float* w3l = (const float*)d_in[12];
  const float* w3r = (const float*)d_in[13];
  const float* b3 = (const float*)d_in[14];

  char* ws = (char*)d_ws;
  size_t off = 0;
  auto alloc = [&](size_t bytes) {
    char* p = ws + off;
    off = (off + bytes + 255) & ~(size_t)255;
    return p;
  };
  unsigned short* xb = (unsigned short*)alloc((size_t)NN * DH * 2);
  unsigned short* meanb = (unsigned short*)alloc((size_t)NN * DH * 2);
  unsigned short* gbuf1 = (unsigned short*)alloc((size_t)NN * DH * 2);
  unsigned short* gbuf2 = (unsigned short*)alloc((size_t)NN * DH * 2);
  unsigned short* w1t = (unsigned short*)alloc(128 * 256 * 2);
  unsigned short* w2t = (unsigned short*)alloc(128 * 256 * 2);
  unsigned short* w3t = (unsigned short*)alloc(128 * 128 * 2);
  // zero region: bcnt | stats1 | stats2 (contiguous)
  int* bcnt = (int*)alloc(NBK * 4);
  float* stats1 = (float*)alloc(2 * DH * 4);
  float* stats2 = (float*)alloc(2 * DH * 4);
  size_t zlen = (char*)(stats2 + 2 * DH) - (char*)bcnt;
  int* deg = (int*)alloc(NN * 4);
  int* rowptr = (int*)alloc((NN + 1) * 4);
  int* adj = (int*)alloc((size_t)NE * 4);
  int* ebuf = (int*)alloc((size_t)NBK * CAPB * 4);
  float* invd = (float*)alloc(NN * 4);
  int* iscan = (int*)alloc(NN * 4);
  int* bsum = (int*)alloc(NB1 * 4);
  float2* bnt1 = (float2*)alloc(DH * 8);

  // ---- prep ----
  hipMemsetAsync(bcnt, 0, zlen, stream);
  k_prep<<<3445, 256, 0, stream>>>(x, w1l, w1r, w2l, w2r, w3l, w3r, xb, w1t, w2t, w3t);
  k_bucket<<<(NE + EPB - 1) / EPB, 256, 0, stream>>>(srcp, dstp, bcnt, ebuf);
  k_hist<<<NBK, 256, 0, stream>>>(bcnt, ebuf, deg, invd);
  k_scan1<<<NB1, 256, 0, stream>>>(deg, iscan, bsum);
  k_scan2<<<1, 256, 0, stream>>>(bsum);
  k_scan3<<<NB1, 256, 0, stream>>>(deg, iscan, bsum, rowptr);
  k_fill2<<<NBK, 256, 0, stream>>>(rowptr, bcnt, ebuf, adj);

  int gemm_blocks = (NN + 127) / 128;
  int agg3_blocks = (NN * 64 + 255) / 256;

  // ---- layer 1 ----
  k_agg<false><<<2 * APB, 256, 0, stream>>>(xb, rowptr, adj, invd, nullptr, meanb);
  k_gemm<true, true, false><<<gemm_blocks, 256, 0, stream>>>(
      meanb, xb, w1t, b1, nullptr, nullptr, nullptr, gbuf1, stats1);
  k_bnprep<<<1, 128, 0, stream>>>(stats1, g1, be1, bnt1);

  // ---- layer 2 (BN1+ReLU fused: agg via table, gemm A-load self-computed) ----
  k_agg<true><<<2 * APB, 256, 0, stream>>>(gbuf1, rowptr, adj, invd, bnt1, meanb);
  k_gemm<true, true, true><<<gemm_blocks, 256, 0, stream>>>(
      meanb, gbuf1, w2t, b2, stats1, g1, be1, gbuf2, stats2);

  // ---- layer 3: transform-first (BN2+ReLU fused into gemm A-load), then aggregate ----
  k_gemm<false, false, true><<<gemm_blocks, 256, 0, stream>>>(
      gbuf2, nullptr, w3t, nullptr, stats2, g2, be2, gbuf1, nullptr);
  k_agg3<<<agg3_blocks, 256, 0, stream>>>(gbuf1, rowptr, adj, invd, b3, (float*)d_out);
}

// Round 11
// 222.310 us; speedup vs baseline: 1.4859x; 1.1222x over previous
//
#include <hip/hip_runtime.h>
#include <hip/hip_bf16.h>

#define NN 50000
#define NE 800000
#define DH 128
#define NB1 196   // ceil(NN/256)
#define NBK 391   // ceil(NN/128) buckets
#define EPB 2048  // edges per bucket-scatter workgroup
#define CAPB 4096 // fixed bucket capacity (mean 2046, ~45 sigma headroom)

typedef __attribute__((ext_vector_type(8))) short bf16x8;
typedef __attribute__((ext_vector_type(4))) float f32x4;
typedef __attribute__((ext_vector_type(8))) unsigned short us8;
typedef __attribute__((ext_vector_type(4))) unsigned short us4;

__device__ __forceinline__ unsigned short f2bf(float f) {
  unsigned int u = __builtin_bit_cast(unsigned int, f);
  unsigned int r = (u + 0x7FFFu + ((u >> 16) & 1u)) >> 16;
  return (unsigned short)r;
}
__device__ __forceinline__ float bf2f(unsigned int h16) {
  unsigned int u = h16 << 16;
  return __builtin_bit_cast(float, u);
}

// ---- merged prep: cvt x->bf16 (blocks 0..3124), w1t (..3252), w2t (..3380), w3t (..3444)
__global__ __launch_bounds__(256) void k_prep(const float* __restrict__ x,
                                              const float* __restrict__ w1l, const float* __restrict__ w1r,
                                              const float* __restrict__ w2l, const float* __restrict__ w2r,
                                              const float* __restrict__ w3l, const float* __restrict__ w3r,
                                              unsigned short* __restrict__ xb,
                                              unsigned short* __restrict__ w1t,
                                              unsigned short* __restrict__ w2t,
                                              unsigned short* __restrict__ w3t) {
  int b = blockIdx.x, t = threadIdx.x;
  if (b < 3125) {
    int i = b * 256 + t;
    const float4* p = reinterpret_cast<const float4*>(x) + (size_t)i * 2;
    float4 a = p[0], bb = p[1];
    us8 o;
    o[0] = f2bf(a.x); o[1] = f2bf(a.y); o[2] = f2bf(a.z); o[3] = f2bf(a.w);
    o[4] = f2bf(bb.x); o[5] = f2bf(bb.y); o[6] = f2bf(bb.z); o[7] = f2bf(bb.w);
    reinterpret_cast<us8*>(xb)[i] = o;
  } else if (b < 3381) {
    bool is1 = b < 3253;
    int idx = (b - (is1 ? 3125 : 3253)) * 256 + t;
    int c = idx >> 8, k = idx & 255;
    const float* wl = is1 ? w1l : w2l;
    const float* wr = is1 ? w1r : w2r;
    float v = (k < DH) ? wl[k * DH + c] : wr[(k - DH) * DH + c];
    (is1 ? w1t : w2t)[idx] = f2bf(v);
  } else {
    int idx = (b - 3381) * 256 + t;
    int c = idx >> 7, k = idx & 127;
    float v = (c < 64) ? w3l[k * 64 + c] : w3r[k * 64 + (c - 64)];
    w3t[idx] = f2bf(v);
  }
}

// ---- bucket scatter: fixed-cap bucket regions, packed (src|dstlow) ----
__global__ __launch_bounds__(256) void k_bucket(const int* __restrict__ src,
                                                const int* __restrict__ dst,
                                                int* __restrict__ bcnt,
                                                int* __restrict__ ebuf) {
  __shared__ int lcnt[NBK], lbase[NBK];
  int t = threadIdx.x;
  for (int b = t; b < NBK; b += 256) lcnt[b] = 0;
  __syncthreads();
  int base = blockIdx.x * EPB;
  int d[8], s[8];
#pragma unroll
  for (int i = 0; i < 8; ++i) {
    int e = base + i * 256 + t;
    if (e < NE) { d[i] = dst[e]; s[i] = src[e]; }
    else d[i] = -1;
  }
#pragma unroll
  for (int i = 0; i < 8; ++i)
    if (d[i] >= 0) atomicAdd(&lcnt[d[i] >> 7], 1);
  __syncthreads();
  for (int b = t; b < NBK; b += 256) {
    int c = lcnt[b];
    lbase[b] = c > 0 ? atomicAdd(&bcnt[b], c) : 0;
    lcnt[b] = 0;
  }
  __syncthreads();
#pragma unroll
  for (int i = 0; i < 8; ++i) {
    if (d[i] >= 0) {
      int b = d[i] >> 7;
      int r = atomicAdd(&lcnt[b], 1);
      ebuf[(size_t)b * CAPB + lbase[b] + r] = s[i] | ((d[i] & 127) << 20);
    }
  }
}

// ---- per-bucket degree histogram -> deg, invd ----
__global__ __launch_bounds__(256) void k_hist(const int* __restrict__ bcnt,
                                              const int* __restrict__ ebuf,
                                              int* __restrict__ deg,
                                              float* __restrict__ invd) {
  int b = blockIdx.x;
  __shared__ int h[128];
  int t = threadIdx.x;
  if (t < 128) h[t] = 0;
  __syncthreads();
  int cnt = bcnt[b];
  const int* eb = ebuf + (size_t)b * CAPB;
  for (int e = t; e < cnt; e += 256)
    atomicAdd(&h[(eb[e] >> 20) & 127], 1);
  __syncthreads();
  int i = (b << 7) + t;
  if (t < 128 && i < NN) {
    int d = h[t];
    deg[i] = d;
    invd[i] = 1.0f / (float)(d > 0 ? d : 1);
  }
}

// ---- scans ----
__global__ void k_scan1(const int* __restrict__ deg, int* __restrict__ iscan,
                        int* __restrict__ bsum) {
  __shared__ int s[256];
  int t = threadIdx.x;
  int i = blockIdx.x * 256 + t;
  int d = (i < NN) ? deg[i] : 0;
  s[t] = d;
  __syncthreads();
  for (int off = 1; off < 256; off <<= 1) {
    int v = (t >= off) ? s[t - off] : 0;
    __syncthreads();
    s[t] += v;
    __syncthreads();
  }
  if (i < NN) iscan[i] = s[t];
  if (t == 255) bsum[blockIdx.x] = s[255];
}

__global__ void k_scan2(int* __restrict__ bsum) {
  __shared__ int s[256];
  int t = threadIdx.x;
  int v = (t < NB1) ? bsum[t] : 0;
  s[t] = v;
  __syncthreads();
  for (int off = 1; off < 256; off <<= 1) {
    int u = (t >= off) ? s[t - off] : 0;
    __syncthreads();
    s[t] += u;
    __syncthreads();
  }
  if (t < NB1) bsum[t] = s[t] - v;
}

__global__ void k_scan3(const int* __restrict__ deg, const int* __restrict__ iscan,
                        const int* __restrict__ bsum, int* __restrict__ rowptr) {
  int i = blockIdx.x * 256 + threadIdx.x;
  if (i >= NN) return;
  int excl = bsum[blockIdx.x] + iscan[i] - deg[i];
  rowptr[i] = excl;
  if (i == 0) rowptr[NN] = NE;
}

// ---- per-bucket CSR fill ----
__global__ __launch_bounds__(256) void k_fill2(const int* __restrict__ rowptr,
                                               const int* __restrict__ bcnt,
                                               const int* __restrict__ ebuf,
                                               int* __restrict__ adj) {
  int b = blockIdx.x;
  int n0 = b << 7;
  int n1 = n0 + 128; if (n1 > NN) n1 = NN;
  __shared__ int cur[128];
  int t = threadIdx.x;
  if (t < n1 - n0) cur[t] = rowptr[n0 + t];
  __syncthreads();
  int cnt = bcnt[b];
  const int* eb = ebuf + (size_t)b * CAPB;
  for (int e = t; e < cnt; e += 256) {
    int p = eb[e];
    int pos = atomicAdd(&cur[(p >> 20) & 127], 1);
    adj[pos] = p & 0xFFFFF;
  }
}

// ---- BN scale/shift table: bnt[c] = (sc, sh) ----
__global__ void k_bnprep(const float* __restrict__ stats, const float* __restrict__ g,
                         const float* __restrict__ be, float2* __restrict__ bnt) {
  int t = threadIdx.x;
  if (t >= 128) return;
  float mu = stats[t] * (1.0f / NN);
  float var = stats[128 + t] * (1.0f / NN) - mu * mu;
  float rs = rsqrtf(var + 1e-5f);
  float scv = rs * g[t];
  bnt[t] = make_float2(scv, be[t] - mu * scv);
}

// ---- gather-mean (champion R6 structure): wave/node, 16-lane quarters x 16B,
//      4 edges in flight; optional BN+ReLU via precomputed table ----
template <bool BNA>
__global__ __launch_bounds__(256) void k_agg(const unsigned short* __restrict__ h,
                                             const int* __restrict__ rowptr,
                                             const int* __restrict__ adj,
                                             const float* __restrict__ invd,
                                             const float2* __restrict__ bnt,
                                             unsigned short* __restrict__ meanb) {
  int wid = (blockIdx.x * blockDim.x + threadIdx.x) >> 6;
  int lane = threadIdx.x & 63;
  if (wid >= NN) return;
  int lo = rowptr[wid], hi = rowptr[wid + 1];
  int q = lane >> 4;
  int c = (lane & 15) << 3;
  float sc[8], sh[8];
  if (BNA) {
#pragma unroll
    for (int j = 0; j < 8; ++j) {
      float2 v = bnt[c + j];
      sc[j] = v.x; sh[j] = v.y;
    }
  }
  float a[8] = {};
  int e = lo;
#pragma unroll 2
  for (; e + 4 <= hi; e += 4) {
    int s = adj[e + q];
    us8 v = *reinterpret_cast<const us8*>(h + (size_t)s * DH + c);
#pragma unroll
    for (int j = 0; j < 8; ++j) {
      float f = bf2f(v[j]);
      a[j] += BNA ? fmaxf(fmaf(f, sc[j], sh[j]), 0.0f) : f;
    }
  }
  if (q < hi - e) {
    int s = adj[e + q];
    us8 v = *reinterpret_cast<const us8*>(h + (size_t)s * DH + c);
#pragma unroll
    for (int j = 0; j < 8; ++j) {
      float f = bf2f(v[j]);
      a[j] += BNA ? fmaxf(fmaf(f, sc[j], sh[j]), 0.0f) : f;
    }
  }
#pragma unroll
  for (int j = 0; j < 8; ++j) {
    a[j] += __shfl_xor(a[j], 16);
    a[j] += __shfl_xor(a[j], 32);
  }
  if (q == 0) {
    float iv = invd[wid];
    us8 o;
#pragma unroll
    for (int j = 0; j < 8; ++j) o[j] = f2bf(a[j] * iv);
    *reinterpret_cast<us8*>(meanb + (size_t)wid * DH + c) = o;
  }
}

// ---- layer-3 agg: gather 64 bf16 cols of t3, + self + b3 -> d_out f32 ----
__global__ __launch_bounds__(256) void k_agg3(const unsigned short* __restrict__ t3,
                                              const int* __restrict__ rowptr,
                                              const int* __restrict__ adj,
                                              const float* __restrict__ invd,
                                              const float* __restrict__ b3,
                                              float* __restrict__ out) {
  int wid = (blockIdx.x * blockDim.x + threadIdx.x) >> 6;
  int lane = threadIdx.x & 63;
  if (wid >= NN) return;
  int lo = rowptr[wid], hi = rowptr[wid + 1];
  int q = lane >> 4;
  int c = (lane & 15) << 2;
  float a[4] = {};
  int e = lo;
#pragma unroll 2
  for (; e + 4 <= hi; e += 4) {
    int s = adj[e + q];
    us4 v = *reinterpret_cast<const us4*>(t3 + (size_t)s * 128 + c);
#pragma unroll
    for (int j = 0; j < 4; ++j) a[j] += bf2f(v[j]);
  }
  if (q < hi - e) {
    int s = adj[e + q];
    us4 v = *reinterpret_cast<const us4*>(t3 + (size_t)s * 128 + c);
#pragma unroll
    for (int j = 0; j < 4; ++j) a[j] += bf2f(v[j]);
  }
#pragma unroll
  for (int j = 0; j < 4; ++j) {
    a[j] += __shfl_xor(a[j], 16);
    a[j] += __shfl_xor(a[j], 32);
  }
  if (q == 0) {
    float iv = invd[wid];
    us4 w = *reinterpret_cast<const us4*>(t3 + (size_t)wid * 128 + 64 + c);
    float4 o;
    o.x = a[0] * iv + bf2f(w[0]) + b3[c + 0];
    o.y = a[1] * iv + bf2f(w[1]) + b3[c + 1];
    o.z = a[2] * iv + bf2f(w[2]) + b3[c + 2];
    o.w = a[3] * iv + bf2f(w[3]) + b3[c + 3];
    *reinterpret_cast<float4*>(out + (size_t)wid * 64 + c) = o;
  }
}

// ---- GEMM with optional fused BN+ReLU on the raw-gemm-out A operand ----
template <bool SPLIT, bool STATS, bool APPLY>
__global__ __launch_bounds__(256) void k_gemm(const unsigned short* __restrict__ Am,
                                              const unsigned short* __restrict__ Ah,
                                              const unsigned short* __restrict__ Wt,
                                              const float* __restrict__ bias,
                                              const float* __restrict__ stA,
                                              const float* __restrict__ gA,
                                              const float* __restrict__ beA,
                                              unsigned short* __restrict__ outb,
                                              float* __restrict__ stats) {
  constexpr int KS = SPLIT ? 8 : 4;
  constexpr int WK = KS * 32;
  __shared__ float asc[DH], ash[DH];
  if (APPLY) {
    int t = threadIdx.x;
    if (t < DH) {
      float mu = stA[t] * (1.0f / NN);
      float var = stA[128 + t] * (1.0f / NN) - mu * mu;
      float rs = rsqrtf(var + 1e-5f);
      float scv = rs * gA[t];
      asc[t] = scv;
      ash[t] = beA[t] - mu * scv;
    }
    __syncthreads();
  }
  int lane = threadIdx.x & 63;
  int w = threadIdx.x >> 6;
  int wr = w >> 1, wc = w & 1;
  int rowbase = blockIdx.x * 128 + wr * 64;
  int colbase = wc * 64;
  int lr = lane & 15, lk = (lane >> 4) << 3;

  f32x4 acc[4][4] = {};
#pragma unroll
  for (int ks = 0; ks < KS; ++ks) {
    const unsigned short* Ab = (!SPLIT || ks < 4) ? Am : Ah;
    bool tr = APPLY && (!SPLIT || ks >= 4);
    int ka = ((ks & 3) << 5) + lk;
    int kw = (ks << 5) + lk;
    bf16x8 af[4], bfr[4];
#pragma unroll
    for (int i = 0; i < 4; ++i) {
      int r = rowbase + i * 16 + lr;
      r = r < NN ? r : NN - 1;
      us8 raw = *reinterpret_cast<const us8*>(Ab + (size_t)r * DH + ka);
      if (tr) {
        us8 o;
#pragma unroll
        for (int j = 0; j < 8; ++j) {
          float f = bf2f(raw[j]);
          o[j] = f2bf(fmaxf(f * asc[ka + j] + ash[ka + j], 0.0f));
        }
        af[i] = __builtin_bit_cast(bf16x8, o);
      } else {
        af[i] = __builtin_bit_cast(bf16x8, raw);
      }
    }
#pragma unroll
    for (int j = 0; j < 4; ++j)
      bfr[j] = *reinterpret_cast<const bf16x8*>(Wt + (size_t)(colbase + j * 16 + lr) * WK + kw);
#pragma unroll
    for (int i = 0; i < 4; ++i)
#pragma unroll
      for (int j = 0; j < 4; ++j)
        acc[i][j] = __builtin_amdgcn_mfma_f32_16x16x32_bf16(af[i], bfr[j], acc[i][j], 0, 0, 0);
  }

  float bv[4];
#pragma unroll
  for (int j = 0; j < 4; ++j) bv[j] = bias ? bias[colbase + j * 16 + lr] : 0.0f;

  float s1[4] = {}, s2[4] = {};
#pragma unroll
  for (int i = 0; i < 4; ++i) {
#pragma unroll
    for (int j = 0; j < 4; ++j) {
      int col = colbase + j * 16 + lr;
#pragma unroll
      for (int r = 0; r < 4; ++r) {
        int row = rowbase + i * 16 + ((lane >> 4) << 2) + r;
        if (row < NN) {
          float val = acc[i][j][r] + bv[j];
          outb[(size_t)row * 128 + col] = f2bf(val);
          if (STATS) { s1[j] += val; s2[j] += val * val; }
        }
      }
    }
  }

  if (STATS) {
    __shared__ float sd[2][128][2];
#pragma unroll
    for (int j = 0; j < 4; ++j) {
      s1[j] += __shfl_xor(s1[j], 16);
      s1[j] += __shfl_xor(s1[j], 32);
      s2[j] += __shfl_xor(s2[j], 16);
      s2[j] += __shfl_xor(s2[j], 32);
    }
    if (lane < 16) {
#pragma unroll
      for (int j = 0; j < 4; ++j) {
        sd[wr][colbase + j * 16 + lane][0] = s1[j];
        sd[wr][colbase + j * 16 + lane][1] = s2[j];
      }
    }
    __syncthreads();
    int t = threadIdx.x;
    if (t < 128) {
      atomicAdd(&stats[t], sd[0][t][0] + sd[1][t][0]);
      atomicAdd(&stats[128 + t], sd[0][t][1] + sd[1][t][1]);
    }
  }
}

extern "C" void kernel_launch(void* const* d_in, const int* in_sizes, int n_in,
                              void* d_out, int out_size, void* d_ws, size_t ws_size,
                              hipStream_t stream) {
  const float* x = (const float*)d_in[0];
  const int* ei = (const int*)d_in[1];
  const int* srcp = ei;
  const int* dstp = ei + NE;
  const float* w1l = (const float*)d_in[2];
  const float* w1r = (const float*)d_in[3];
  const float* b1 = (const float*)d_in[4];
  const float* g1 = (const float*)d_in[5];
  const float* be1 = (const float*)d_in[6];
  const float* w2l = (const float*)d_in[7];
  const float* w2r = (const float*)d_in[8];
  const float* b2 = (const float*)d_in[9];
  const float* g2 = (const float*)d_in[10];
  const float* be2 = (const float*)d_in[11];
  const float* w3l = (const float*)d_in[12];
  const float* w3r = (const float*)d_in[13];
  const float* b3 = (const float*)d_in[14];

  char* ws = (char*)d_ws;
  size_t off = 0;
  auto alloc = [&](size_t bytes) {
    char* p = ws + off;
    off = (off + bytes + 255) & ~(size_t)255;
    return p;
  };
  unsigned short* xb = (unsigned short*)alloc((size_t)NN * DH * 2);
  unsigned short* meanb = (unsigned short*)alloc((size_t)NN * DH * 2);
  unsigned short* gbuf1 = (unsigned short*)alloc((size_t)NN * DH * 2);
  unsigned short* gbuf2 = (unsigned short*)alloc((size_t)NN * DH * 2);
  unsigned short* w1t = (unsigned short*)alloc(128 * 256 * 2);
  unsigned short* w2t = (unsigned short*)alloc(128 * 256 * 2);
  unsigned short* w3t = (unsigned short*)alloc(128 * 128 * 2);
  // zero region: bcnt | stats1 | stats2 (contiguous)
  int* bcnt = (int*)alloc(NBK * 4);
  float* stats1 = (float*)alloc(2 * DH * 4);
  float* stats2 = (float*)alloc(2 * DH * 4);
  size_t zlen = (char*)(stats2 + 2 * DH) - (char*)bcnt;
  int* deg = (int*)alloc(NN * 4);
  int* rowptr = (int*)alloc((NN + 1) * 4);
  int* adj = (int*)alloc((size_t)NE * 4);
  int* ebuf = (int*)alloc((size_t)NBK * CAPB * 4);
  float* invd = (float*)alloc(NN * 4);
  int* iscan = (int*)alloc(NN * 4);
  int* bsum = (int*)alloc(NB1 * 4);
  float2* bnt1 = (float2*)alloc(DH * 8);

  // ---- prep ----
  hipMemsetAsync(bcnt, 0, zlen, stream);
  k_prep<<<3445, 256, 0, stream>>>(x, w1l, w1r, w2l, w2r, w3l, w3r, xb, w1t, w2t, w3t);
  k_bucket<<<(NE + EPB - 1) / EPB, 256, 0, stream>>>(srcp, dstp, bcnt, ebuf);
  k_hist<<<NBK, 256, 0, stream>>>(bcnt, ebuf, deg, invd);
  k_scan1<<<NB1, 256, 0, stream>>>(deg, iscan, bsum);
  k_scan2<<<1, 256, 0, stream>>>(bsum);
  k_scan3<<<NB1, 256, 0, stream>>>(deg, iscan, bsum, rowptr);
  k_fill2<<<NBK, 256, 0, stream>>>(rowptr, bcnt, ebuf, adj);

  int agg_blocks = (NN * 64 + 255) / 256;
  int gemm_blocks = (NN + 127) / 128;

  // ---- layer 1 ----
  k_agg<false><<<agg_blocks, 256, 0, stream>>>(xb, rowptr, adj, invd, nullptr, meanb);
  k_gemm<true, true, false><<<gemm_blocks, 256, 0, stream>>>(
      meanb, xb, w1t, b1, nullptr, nullptr, nullptr, gbuf1, stats1);
  k_bnprep<<<1, 128, 0, stream>>>(stats1, g1, be1, bnt1);

  // ---- layer 2 (BN1+ReLU fused: agg via table, gemm A-load self-computed) ----
  k_agg<true><<<agg_blocks, 256, 0, stream>>>(gbuf1, rowptr, adj, invd, bnt1, meanb);
  k_gemm<true, true, true><<<gemm_blocks, 256, 0, stream>>>(
      meanb, gbuf1, w2t, b2, stats1, g1, be1, gbuf2, stats2);

  // ---- layer 3: transform-first (BN2+ReLU fused into gemm A-load), then aggregate ----
  k_gemm<false, false, true><<<gemm_blocks, 256, 0, stream>>>(
      gbuf2, nullptr, w3t, nullptr, stats2, g2, be2, gbuf1, nullptr);
  k_agg3<<<agg_blocks, 256, 0, stream>>>(gbuf1, rowptr, adj, invd, b3, (float*)d_out);
}

// Round 12
// 217.867 us; speedup vs baseline: 1.5162x; 1.0204x over previous
//
#include <hip/hip_runtime.h>
#include <hip/hip_bf16.h>

#define NN 50000
#define NE 800000
#define DH 128
#define NB1 196   // ceil(NN/256)
#define NBK 391   // ceil(NN/128) buckets
#define EPB 2048  // edges per bucket-scatter workgroup
#define CAPB 4096 // fixed bucket capacity (mean 2046, ~45 sigma headroom)

typedef __attribute__((ext_vector_type(8))) short bf16x8;
typedef __attribute__((ext_vector_type(4))) float f32x4;
typedef __attribute__((ext_vector_type(2))) float f32x2;
typedef __attribute__((ext_vector_type(8))) unsigned short us8;
typedef __attribute__((ext_vector_type(4))) unsigned short us4;

__device__ __forceinline__ unsigned short f2bf(float f) {
  unsigned int u = __builtin_bit_cast(unsigned int, f);
  unsigned int r = (u + 0x7FFFu + ((u >> 16) & 1u)) >> 16;
  return (unsigned short)r;
}
__device__ __forceinline__ float bf2f(unsigned int h16) {
  unsigned int u = h16 << 16;
  return __builtin_bit_cast(float, u);
}
// 4 fp8 (one dword) -> 4 f32 via HW packed converts
__device__ __forceinline__ void fp8x4_to_f32(unsigned int w, float* o) {
  f32x2 lo = __builtin_amdgcn_cvt_pk_f32_fp8(w, false);
  f32x2 hi = __builtin_amdgcn_cvt_pk_f32_fp8(w, true);
  o[0] = lo[0]; o[1] = lo[1]; o[2] = hi[0]; o[3] = hi[1];
}
__device__ __forceinline__ unsigned int f32x4_to_fp8(float a, float b, float c, float d) {
  unsigned int w = __builtin_amdgcn_cvt_pk_fp8_f32(a, b, 0, false);
  w = __builtin_amdgcn_cvt_pk_fp8_f32(c, d, w, true);
  return w;
}
__device__ __forceinline__ unsigned char f32_to_fp8(float v) {
  return (unsigned char)(__builtin_amdgcn_cvt_pk_fp8_f32(v, v, 0, false) & 0xFF);
}

// ---- merged prep: cvt x->bf16+fp8 (blocks 0..3124), w1t (..3252), w2t (..3380), w3t (..3444)
__global__ __launch_bounds__(256) void k_prep(const float* __restrict__ x,
                                              const float* __restrict__ w1l, const float* __restrict__ w1r,
                                              const float* __restrict__ w2l, const float* __restrict__ w2r,
                                              const float* __restrict__ w3l, const float* __restrict__ w3r,
                                              unsigned short* __restrict__ xb,
                                              unsigned char* __restrict__ xb8,
                                              unsigned short* __restrict__ w1t,
                                              unsigned short* __restrict__ w2t,
                                              unsigned short* __restrict__ w3t) {
  int b = blockIdx.x, t = threadIdx.x;
  if (b < 3125) {
    int i = b * 256 + t;
    const float4* p = reinterpret_cast<const float4*>(x) + (size_t)i * 2;
    float4 a = p[0], bb = p[1];
    us8 o;
    o[0] = f2bf(a.x); o[1] = f2bf(a.y); o[2] = f2bf(a.z); o[3] = f2bf(a.w);
    o[4] = f2bf(bb.x); o[5] = f2bf(bb.y); o[6] = f2bf(bb.z); o[7] = f2bf(bb.w);
    reinterpret_cast<us8*>(xb)[i] = o;
    uint2 o8;
    o8.x = f32x4_to_fp8(a.x, a.y, a.z, a.w);
    o8.y = f32x4_to_fp8(bb.x, bb.y, bb.z, bb.w);
    reinterpret_cast<uint2*>(xb8)[i] = o8;
  } else if (b < 3381) {
    bool is1 = b < 3253;
    int idx = (b - (is1 ? 3125 : 3253)) * 256 + t;
    int c = idx >> 8, k = idx & 255;
    const float* wl = is1 ? w1l : w2l;
    const float* wr = is1 ? w1r : w2r;
    float v = (k < DH) ? wl[k * DH + c] : wr[(k - DH) * DH + c];
    (is1 ? w1t : w2t)[idx] = f2bf(v);
  } else {
    int idx = (b - 3381) * 256 + t;
    int c = idx >> 7, k = idx & 127;
    float v = (c < 64) ? w3l[k * 64 + c] : w3r[k * 64 + (c - 64)];
    w3t[idx] = f2bf(v);
  }
}

// ---- bucket scatter: fixed-cap bucket regions, packed (src|dstlow) ----
__global__ __launch_bounds__(256) void k_bucket(const int* __restrict__ src,
                                                const int* __restrict__ dst,
                                                int* __restrict__ bcnt,
                                                int* __restrict__ ebuf) {
  __shared__ int lcnt[NBK], lbase[NBK];
  int t = threadIdx.x;
  for (int b = t; b < NBK; b += 256) lcnt[b] = 0;
  __syncthreads();
  int base = blockIdx.x * EPB;
  int d[8], s[8];
#pragma unroll
  for (int i = 0; i < 8; ++i) {
    int e = base + i * 256 + t;
    if (e < NE) { d[i] = dst[e]; s[i] = src[e]; }
    else d[i] = -1;
  }
#pragma unroll
  for (int i = 0; i < 8; ++i)
    if (d[i] >= 0) atomicAdd(&lcnt[d[i] >> 7], 1);
  __syncthreads();
  for (int b = t; b < NBK; b += 256) {
    int c = lcnt[b];
    lbase[b] = c > 0 ? atomicAdd(&bcnt[b], c) : 0;
    lcnt[b] = 0;
  }
  __syncthreads();
#pragma unroll
  for (int i = 0; i < 8; ++i) {
    if (d[i] >= 0) {
      int b = d[i] >> 7;
      int r = atomicAdd(&lcnt[b], 1);
      ebuf[(size_t)b * CAPB + lbase[b] + r] = s[i] | ((d[i] & 127) << 20);
    }
  }
}

// ---- per-bucket degree histogram -> deg, invd ----
__global__ __launch_bounds__(256) void k_hist(const int* __restrict__ bcnt,
                                              const int* __restrict__ ebuf,
                                              int* __restrict__ deg,
                                              float* __restrict__ invd) {
  int b = blockIdx.x;
  __shared__ int h[128];
  int t = threadIdx.x;
  if (t < 128) h[t] = 0;
  __syncthreads();
  int cnt = bcnt[b];
  const int* eb = ebuf + (size_t)b * CAPB;
  for (int e = t; e < cnt; e += 256)
    atomicAdd(&h[(eb[e] >> 20) & 127], 1);
  __syncthreads();
  int i = (b << 7) + t;
  if (t < 128 && i < NN) {
    int d = h[t];
    deg[i] = d;
    invd[i] = 1.0f / (float)(d > 0 ? d : 1);
  }
}

// ---- scans ----
__global__ void k_scan1(const int* __restrict__ deg, int* __restrict__ iscan,
                        int* __restrict__ bsum) {
  __shared__ int s[256];
  int t = threadIdx.x;
  int i = blockIdx.x * 256 + t;
  int d = (i < NN) ? deg[i] : 0;
  s[t] = d;
  __syncthreads();
  for (int off = 1; off < 256; off <<= 1) {
    int v = (t >= off) ? s[t - off] : 0;
    __syncthreads();
    s[t] += v;
    __syncthreads();
  }
  if (i < NN) iscan[i] = s[t];
  if (t == 255) bsum[blockIdx.x] = s[255];
}

__global__ void k_scan2(int* __restrict__ bsum) {
  __shared__ int s[256];
  int t = threadIdx.x;
  int v = (t < NB1) ? bsum[t] : 0;
  s[t] = v;
  __syncthreads();
  for (int off = 1; off < 256; off <<= 1) {
    int u = (t >= off) ? s[t - off] : 0;
    __syncthreads();
    s[t] += u;
    __syncthreads();
  }
  if (t < NB1) bsum[t] = s[t] - v;
}

__global__ void k_scan3(const int* __restrict__ deg, const int* __restrict__ iscan,
                        const int* __restrict__ bsum, int* __restrict__ rowptr) {
  int i = blockIdx.x * 256 + threadIdx.x;
  if (i >= NN) return;
  int excl = bsum[blockIdx.x] + iscan[i] - deg[i];
  rowptr[i] = excl;
  if (i == 0) rowptr[NN] = NE;
}

// ---- per-bucket CSR fill ----
__global__ __launch_bounds__(256) void k_fill2(const int* __restrict__ rowptr,
                                               const int* __restrict__ bcnt,
                                               const int* __restrict__ ebuf,
                                               int* __restrict__ adj) {
  int b = blockIdx.x;
  int n0 = b << 7;
  int n1 = n0 + 128; if (n1 > NN) n1 = NN;
  __shared__ int cur[128];
  int t = threadIdx.x;
  if (t < n1 - n0) cur[t] = rowptr[n0 + t];
  __syncthreads();
  int cnt = bcnt[b];
  const int* eb = ebuf + (size_t)b * CAPB;
  for (int e = t; e < cnt; e += 256) {
    int p = eb[e];
    int pos = atomicAdd(&cur[(p >> 20) & 127], 1);
    adj[pos] = p & 0xFFFFF;
  }
}

// ---- BN scale/shift table: bnt[c] = (sc, sh) ----
__global__ void k_bnprep(const float* __restrict__ stats, const float* __restrict__ g,
                         const float* __restrict__ be, float2* __restrict__ bnt) {
  int t = threadIdx.x;
  if (t >= 128) return;
  float mu = stats[t] * (1.0f / NN);
  float var = stats[128 + t] * (1.0f / NN) - mu * mu;
  float rs = rsqrtf(var + 1e-5f);
  float scv = rs * g[t];
  bnt[t] = make_float2(scv, be[t] - mu * scv);
}

// ---- fp8 gather-mean: wave/node, 16-lane quarters x 8B (one 128B line/edge),
//      4 edges in flight; optional BN+ReLU via table; f32 accum; bf16 mean out ----
template <bool BNA>
__global__ __launch_bounds__(256) void k_agg8(const unsigned char* __restrict__ h8,
                                              const int* __restrict__ rowptr,
                                              const int* __restrict__ adj,
                                              const float* __restrict__ invd,
                                              const float2* __restrict__ bnt,
                                              unsigned short* __restrict__ meanb) {
  int wid = (blockIdx.x * blockDim.x + threadIdx.x) >> 6;
  int lane = threadIdx.x & 63;
  if (wid >= NN) return;
  int lo = rowptr[wid], hi = rowptr[wid + 1];
  int q = lane >> 4;
  int c = (lane & 15) << 3;
  float sc[8], sh[8];
  if (BNA) {
#pragma unroll
    for (int j = 0; j < 8; ++j) {
      float2 v = bnt[c + j];
      sc[j] = v.x; sh[j] = v.y;
    }
  }
  const unsigned char* hb = h8 + c;
  float a[8] = {};
  int e = lo;
#pragma unroll 2
  for (; e + 4 <= hi; e += 4) {
    int s = adj[e + q];
    uint2 v = *reinterpret_cast<const uint2*>(hb + (size_t)s * DH);
    float f[8];
    fp8x4_to_f32(v.x, f);
    fp8x4_to_f32(v.y, f + 4);
#pragma unroll
    for (int j = 0; j < 8; ++j)
      a[j] += BNA ? fmaxf(fmaf(f[j], sc[j], sh[j]), 0.0f) : f[j];
  }
  if (q < hi - e) {
    int s = adj[e + q];
    uint2 v = *reinterpret_cast<const uint2*>(hb + (size_t)s * DH);
    float f[8];
    fp8x4_to_f32(v.x, f);
    fp8x4_to_f32(v.y, f + 4);
#pragma unroll
    for (int j = 0; j < 8; ++j)
      a[j] += BNA ? fmaxf(fmaf(f[j], sc[j], sh[j]), 0.0f) : f[j];
  }
#pragma unroll
  for (int j = 0; j < 8; ++j) {
    a[j] += __shfl_xor(a[j], 16);
    a[j] += __shfl_xor(a[j], 32);
  }
  if (q == 0) {
    float iv = invd[wid];
    us8 o;
#pragma unroll
    for (int j = 0; j < 8; ++j) o[j] = f2bf(a[j] * iv);
    *reinterpret_cast<us8*>(meanb + (size_t)wid * DH + c) = o;
  }
}

// ---- layer-3 agg: gather 64 bf16 cols of t3 (one line/edge), + self + b3 -> f32 ----
__global__ __launch_bounds__(256) void k_agg3(const unsigned short* __restrict__ t3,
                                              const int* __restrict__ rowptr,
                                              const int* __restrict__ adj,
                                              const float* __restrict__ invd,
                                              const float* __restrict__ b3,
                                              float* __restrict__ out) {
  int wid = (blockIdx.x * blockDim.x + threadIdx.x) >> 6;
  int lane = threadIdx.x & 63;
  if (wid >= NN) return;
  int lo = rowptr[wid], hi = rowptr[wid + 1];
  int q = lane >> 4;
  int c = (lane & 15) << 2;
  float a[4] = {};
  int e = lo;
#pragma unroll 2
  for (; e + 4 <= hi; e += 4) {
    int s = adj[e + q];
    us4 v = *reinterpret_cast<const us4*>(t3 + (size_t)s * 128 + c);
#pragma unroll
    for (int j = 0; j < 4; ++j) a[j] += bf2f(v[j]);
  }
  if (q < hi - e) {
    int s = adj[e + q];
    us4 v = *reinterpret_cast<const us4*>(t3 + (size_t)s * 128 + c);
#pragma unroll
    for (int j = 0; j < 4; ++j) a[j] += bf2f(v[j]);
  }
#pragma unroll
  for (int j = 0; j < 4; ++j) {
    a[j] += __shfl_xor(a[j], 16);
    a[j] += __shfl_xor(a[j], 32);
  }
  if (q == 0) {
    float iv = invd[wid];
    us4 w = *reinterpret_cast<const us4*>(t3 + (size_t)wid * 128 + 64 + c);
    float4 o;
    o.x = a[0] * iv + bf2f(w[0]) + b3[c + 0];
    o.y = a[1] * iv + bf2f(w[1]) + b3[c + 1];
    o.z = a[2] * iv + bf2f(w[2]) + b3[c + 2];
    o.w = a[3] * iv + bf2f(w[3]) + b3[c + 3];
    *reinterpret_cast<float4*>(out + (size_t)wid * 64 + c) = o;
  }
}

// ---- GEMM; optional fused BN+ReLU on A; optional fp8 shadow of raw output ----
template <bool SPLIT, bool STATS, bool APPLY>
__global__ __launch_bounds__(256) void k_gemm(const unsigned short* __restrict__ Am,
                                              const unsigned short* __restrict__ Ah,
                                              const unsigned short* __restrict__ Wt,
                                              const float* __restrict__ bias,
                                              const float* __restrict__ stA,
                                              const float* __restrict__ gA,
                                              const float* __restrict__ beA,
                                              unsigned short* __restrict__ outb,
                                              float* __restrict__ stats,
                                              unsigned char* __restrict__ out8) {
  constexpr int KS = SPLIT ? 8 : 4;
  constexpr int WK = KS * 32;
  __shared__ float asc[DH], ash[DH];
  if (APPLY) {
    int t = threadIdx.x;
    if (t < DH) {
      float mu = stA[t] * (1.0f / NN);
      float var = stA[128 + t] * (1.0f / NN) - mu * mu;
      float rs = rsqrtf(var + 1e-5f);
      float scv = rs * gA[t];
      asc[t] = scv;
      ash[t] = beA[t] - mu * scv;
    }
    __syncthreads();
  }
  int lane = threadIdx.x & 63;
  int w = threadIdx.x >> 6;
  int wr = w >> 1, wc = w & 1;
  int rowbase = blockIdx.x * 128 + wr * 64;
  int colbase = wc * 64;
  int lr = lane & 15, lk = (lane >> 4) << 3;

  f32x4 acc[4][4] = {};
#pragma unroll
  for (int ks = 0; ks < KS; ++ks) {
    const unsigned short* Ab = (!SPLIT || ks < 4) ? Am : Ah;
    bool tr = APPLY && (!SPLIT || ks >= 4);
    int ka = ((ks & 3) << 5) + lk;
    int kw = (ks << 5) + lk;
    bf16x8 af[4], bfr[4];
#pragma unroll
    for (int i = 0; i < 4; ++i) {
      int r = rowbase + i * 16 + lr;
      r = r < NN ? r : NN - 1;
      us8 raw = *reinterpret_cast<const us8*>(Ab + (size_t)r * DH + ka);
      if (tr) {
        us8 o;
#pragma unroll
        for (int j = 0; j < 8; ++j) {
          float f = bf2f(raw[j]);
          o[j] = f2bf(fmaxf(f * asc[ka + j] + ash[ka + j], 0.0f));
        }
        af[i] = __builtin_bit_cast(bf16x8, o);
      } else {
        af[i] = __builtin_bit_cast(bf16x8, raw);
      }
    }
#pragma unroll
    for (int j = 0; j < 4; ++j)
      bfr[j] = *reinterpret_cast<const bf16x8*>(Wt + (size_t)(colbase + j * 16 + lr) * WK + kw);
#pragma unroll
    for (int i = 0; i < 4; ++i)
#pragma unroll
      for (int j = 0; j < 4; ++j)
        acc[i][j] = __builtin_amdgcn_mfma_f32_16x16x32_bf16(af[i], bfr[j], acc[i][j], 0, 0, 0);
  }

  float bv[4];
#pragma unroll
  for (int j = 0; j < 4; ++j) bv[j] = bias ? bias[colbase + j * 16 + lr] : 0.0f;

  float s1[4] = {}, s2[4] = {};
#pragma unroll
  for (int i = 0; i < 4; ++i) {
#pragma unroll
    for (int j = 0; j < 4; ++j) {
      int col = colbase + j * 16 + lr;
#pragma unroll
      for (int r = 0; r < 4; ++r) {
        int row = rowbase + i * 16 + ((lane >> 4) << 2) + r;
        if (row < NN) {
          float val = acc[i][j][r] + bv[j];
          outb[(size_t)row * 128 + col] = f2bf(val);
          if (out8) out8[(size_t)row * 128 + col] = f32_to_fp8(val);
          if (STATS) { s1[j] += val; s2[j] += val * val; }
        }
      }
    }
  }

  if (STATS) {
    __shared__ float sd[2][128][2];
#pragma unroll
    for (int j = 0; j < 4; ++j) {
      s1[j] += __shfl_xor(s1[j], 16);
      s1[j] += __shfl_xor(s1[j], 32);
      s2[j] += __shfl_xor(s2[j], 16);
      s2[j] += __shfl_xor(s2[j], 32);
    }
    if (lane < 16) {
#pragma unroll
      for (int j = 0; j < 4; ++j) {
        sd[wr][colbase + j * 16 + lane][0] = s1[j];
        sd[wr][colbase + j * 16 + lane][1] = s2[j];
      }
    }
    __syncthreads();
    int t = threadIdx.x;
    if (t < 128) {
      atomicAdd(&stats[t], sd[0][t][0] + sd[1][t][0]);
      atomicAdd(&stats[128 + t], sd[0][t][1] + sd[1][t][1]);
    }
  }
}

extern "C" void kernel_launch(void* const* d_in, const int* in_sizes, int n_in,
                              void* d_out, int out_size, void* d_ws, size_t ws_size,
                              hipStream_t stream) {
  const float* x = (const float*)d_in[0];
  const int* ei = (const int*)d_in[1];
  const int* srcp = ei;
  const int* dstp = ei + NE;
  const float* w1l = (const float*)d_in[2];
  const float* w1r = (const float*)d_in[3];
  const float* b1 = (const float*)d_in[4];
  const float* g1 = (const float*)d_in[5];
  const float* be1 = (const float*)d_in[6];
  const float* w2l = (const float*)d_in[7];
  const float* w2r = (const float*)d_in[8];
  const float* b2 = (const float*)d_in[9];
  const float* g2 = (const float*)d_in[10];
  const float* be2 = (const float*)d_in[11];
  const float* w3l = (const float*)d_in[12];
  const float* w3r = (const float*)d_in[13];
  const float* b3 = (const float*)d_in[14];

  char* ws = (char*)d_ws;
  size_t off = 0;
  auto alloc = [&](size_t bytes) {
    char* p = ws + off;
    off = (off + bytes + 255) & ~(size_t)255;
    return p;
  };
  unsigned short* xb = (unsigned short*)alloc((size_t)NN * DH * 2);
  unsigned short* meanb = (unsigned short*)alloc((size_t)NN * DH * 2);
  unsigned short* gbuf1 = (unsigned short*)alloc((size_t)NN * DH * 2);
  unsigned short* gbuf2 = (unsigned short*)alloc((size_t)NN * DH * 2);
  unsigned char* xb8 = (unsigned char*)alloc((size_t)NN * DH);
  unsigned char* g1raw8 = (unsigned char*)alloc((size_t)NN * DH);
  unsigned short* w1t = (unsigned short*)alloc(128 * 256 * 2);
  unsigned short* w2t = (unsigned short*)alloc(128 * 256 * 2);
  unsigned short* w3t = (unsigned short*)alloc(128 * 128 * 2);
  // zero region: bcnt | stats1 | stats2 (contiguous)
  int* bcnt = (int*)alloc(NBK * 4);
  float* stats1 = (float*)alloc(2 * DH * 4);
  float* stats2 = (float*)alloc(2 * DH * 4);
  size_t zlen = (char*)(stats2 + 2 * DH) - (char*)bcnt;
  int* deg = (int*)alloc(NN * 4);
  int* rowptr = (int*)alloc((NN + 1) * 4);
  int* adj = (int*)alloc((size_t)NE * 4);
  int* ebuf = (int*)alloc((size_t)NBK * CAPB * 4);
  float* invd = (float*)alloc(NN * 4);
  int* iscan = (int*)alloc(NN * 4);
  int* bsum = (int*)alloc(NB1 * 4);
  float2* bnt1 = (float2*)alloc(DH * 8);

  // ---- prep ----
  hipMemsetAsync(bcnt, 0, zlen, stream);
  k_prep<<<3445, 256, 0, stream>>>(x, w1l, w1r, w2l, w2r, w3l, w3r, xb, xb8, w1t, w2t, w3t);
  k_bucket<<<(NE + EPB - 1) / EPB, 256, 0, stream>>>(srcp, dstp, bcnt, ebuf);
  k_hist<<<NBK, 256, 0, stream>>>(bcnt, ebuf, deg, invd);
  k_scan1<<<NB1, 256, 0, stream>>>(deg, iscan, bsum);
  k_scan2<<<1, 256, 0, stream>>>(bsum);
  k_scan3<<<NB1, 256, 0, stream>>>(deg, iscan, bsum, rowptr);
  k_fill2<<<NBK, 256, 0, stream>>>(rowptr, bcnt, ebuf, adj);

  int agg_blocks = (NN * 64 + 255) / 256;
  int gemm_blocks = (NN + 127) / 128;

  // ---- layer 1 (fp8 gather of x; bf16 self; fp8 shadow of raw out) ----
  k_agg8<false><<<agg_blocks, 256, 0, stream>>>(xb8, rowptr, adj, invd, nullptr, meanb);
  k_gemm<true, true, false><<<gemm_blocks, 256, 0, stream>>>(
      meanb, xb, w1t, b1, nullptr, nullptr, nullptr, gbuf1, stats1, g1raw8);
  k_bnprep<<<1, 128, 0, stream>>>(stats1, g1, be1, bnt1);

  // ---- layer 2 (fp8 gather of raw h1 with fused BN+ReLU; bf16 self with APPLY) ----
  k_agg8<true><<<agg_blocks, 256, 0, stream>>>(g1raw8, rowptr, adj, invd, bnt1, meanb);
  k_gemm<true, true, true><<<gemm_blocks, 256, 0, stream>>>(
      meanb, gbuf1, w2t, b2, stats1, g1, be1, gbuf2, stats2, nullptr);

  // ---- layer 3: transform-first (BN2+ReLU fused into gemm A-load), then aggregate ----
  k_gemm<false, false, true><<<gemm_blocks, 256, 0, stream>>>(
      gbuf2, nullptr, w3t, nullptr, stats2, g2, be2, gbuf1, nullptr, nullptr);
  k_agg3<<<agg_blocks, 256, 0, stream>>>(gbuf1, rowptr, adj, invd, b3, (float*)d_out);
}